// Round 6
// baseline (7474.638 us; speedup 1.0000x reference)
//
#include <hip/hip_runtime.h>
#include <stdint.h>

#define S_LEN 2048
#define B_SZ  64
#define I_SZ  512
#define H_SZ  512

typedef __attribute__((ext_vector_type(8))) short bf16x8;
typedef __attribute__((ext_vector_type(4))) float f32x4;

// f32 -> bf16 (RNE), no header dependency
__device__ __forceinline__ uint16_t f2b(float x) {
    uint32_t u = __float_as_uint(x);
    uint32_t r = (u + 0x7fffu + ((u >> 16) & 1u)) >> 16;
    return (uint16_t)r;
}

__device__ __forceinline__ float tfun(float v) {
    float e = __expf(2.f * v);
    return 1.f - 2.f / (e + 1.f);
}

// ---------------- kernel 1: convert weights to bf16 in ws ----------------
__global__ void cvt_weights_kernel(const float* __restrict__ wih,
                                   const float* __restrict__ whh,
                                   uint16_t* __restrict__ wihb,
                                   uint16_t* __restrict__ whhb) {
    int i = (blockIdx.x * blockDim.x + threadIdx.x) * 4;
    float4 a = *reinterpret_cast<const float4*>(wih + i);
    float4 b = *reinterpret_cast<const float4*>(whh + i);
    union { uint16_t u[4]; uint2 v; } pa, pb;
    pa.u[0] = f2b(a.x); pa.u[1] = f2b(a.y); pa.u[2] = f2b(a.z); pa.u[3] = f2b(a.w);
    pb.u[0] = f2b(b.x); pb.u[1] = f2b(b.y); pb.u[2] = f2b(b.z); pb.u[3] = f2b(b.w);
    *reinterpret_cast<uint2*>(wihb + i) = pa.v;
    *reinterpret_cast<uint2*>(whhb + i) = pb.v;
}

// ---------------- kernel 2: x_proj GEMM  xp[sb,h] = input[sb,:] . Wih[h,:] + bias ---
#define BM 128
#define BN 128
#define BK 32

__launch_bounds__(256)
__global__ void xproj_gemm_kernel(const float* __restrict__ inp,      // [SB, I] f32
                                  const uint16_t* __restrict__ wihb,  // [H, I] bf16
                                  const float* __restrict__ bih,
                                  const float* __restrict__ bhh,
                                  float* __restrict__ xp)             // [SB, H] f32 (= d_out)
{
    __shared__ __align__(16) uint16_t Asm[2][BM * BK];
    __shared__ __align__(16) uint16_t Bsm[2][BN * BK];

    const int tid  = threadIdx.x;
    const int lane = tid & 63;
    const int w    = tid >> 6;
    const int wm   = (w >> 1) * 64;
    const int wn   = (w & 1) * 64;
    const int bid  = blockIdx.x;
    const int m0   = (bid >> 2) * BM;
    const int n0   = (bid & 3) * BN;

    const int srow  = tid >> 1;
    const int shalf = (tid & 1) * 16;

    float bsum[4];
#pragma unroll
    for (int nn = 0; nn < 4; ++nn) {
        int col = n0 + wn + nn * 16 + (lane & 15);
        bsum[nn] = bih[col] + bhh[col];
    }

    f32x4 acc[4][4];
#pragma unroll
    for (int mm = 0; mm < 4; ++mm)
#pragma unroll
        for (int nn = 0; nn < 4; ++nn)
            acc[mm][nn] = f32x4{0.f, 0.f, 0.f, 0.f};

    float4 ar[4];
    bf16x8 br[2];

    auto loadA = [&](int kt) {
        const float* g = inp + (size_t)(m0 + srow) * I_SZ + kt * BK + shalf;
#pragma unroll
        for (int q = 0; q < 4; ++q) ar[q] = *reinterpret_cast<const float4*>(g + q * 4);
    };
    auto loadB = [&](int kt) {
        const uint16_t* g = wihb + (size_t)(n0 + srow) * I_SZ + kt * BK + shalf;
        br[0] = *reinterpret_cast<const bf16x8*>(g);
        br[1] = *reinterpret_cast<const bf16x8*>(g + 8);
    };
    auto writeA = [&](int buf) {
        alignas(16) uint16_t tmp[16];
#pragma unroll
        for (int q = 0; q < 4; ++q) {
            tmp[q * 4 + 0] = f2b(ar[q].x); tmp[q * 4 + 1] = f2b(ar[q].y);
            tmp[q * 4 + 2] = f2b(ar[q].z); tmp[q * 4 + 3] = f2b(ar[q].w);
        }
        *reinterpret_cast<bf16x8*>(&Asm[buf][srow * BK + shalf])     = *reinterpret_cast<bf16x8*>(tmp);
        *reinterpret_cast<bf16x8*>(&Asm[buf][srow * BK + shalf + 8]) = *reinterpret_cast<bf16x8*>(tmp + 8);
    };
    auto writeB = [&](int buf) {
        *reinterpret_cast<bf16x8*>(&Bsm[buf][srow * BK + shalf])     = br[0];
        *reinterpret_cast<bf16x8*>(&Bsm[buf][srow * BK + shalf + 8]) = br[1];
    };

    loadA(0); loadB(0); writeA(0); writeB(0);
    __syncthreads();

    for (int kt = 0; kt < I_SZ / BK; ++kt) {
        const int cur = kt & 1;
        const bool more = (kt + 1) < I_SZ / BK;
        if (more) { loadA(kt + 1); loadB(kt + 1); }

        bf16x8 afrag[4], bfrag[4];
#pragma unroll
        for (int mm = 0; mm < 4; ++mm)
            afrag[mm] = *reinterpret_cast<const bf16x8*>(
                &Asm[cur][(wm + mm * 16 + (lane & 15)) * BK + (lane >> 4) * 8]);
#pragma unroll
        for (int nn = 0; nn < 4; ++nn)
            bfrag[nn] = *reinterpret_cast<const bf16x8*>(
                &Bsm[cur][(wn + nn * 16 + (lane & 15)) * BK + (lane >> 4) * 8]);
#pragma unroll
        for (int mm = 0; mm < 4; ++mm)
#pragma unroll
            for (int nn = 0; nn < 4; ++nn)
                acc[mm][nn] = __builtin_amdgcn_mfma_f32_16x16x32_bf16(
                    afrag[mm], bfrag[nn], acc[mm][nn], 0, 0, 0);

        if (more) { writeA(cur ^ 1); writeB(cur ^ 1); }
        __syncthreads();
    }

#pragma unroll
    for (int mm = 0; mm < 4; ++mm) {
        const int rbase = m0 + wm + mm * 16 + (lane >> 4) * 4;
#pragma unroll
        for (int nn = 0; nn < 4; ++nn) {
            const int col = n0 + wn + nn * 16 + (lane & 15);
#pragma unroll
            for (int r = 0; r < 4; ++r)
                xp[(size_t)(rbase + r) * H_SZ + col] = acc[mm][nn][r] + bsum[nn];
        }
    }
}

// ---------------- kernel 3: recurrence. One block per batch element. --------------
// 8 waves; wave w owns rows [w*64, w*64+64). W_hh fragments: 60 of 64 pinned in
// AGPRs (240 AGPRs, "a" constraint), last 4 (subtile D, kt=12..15) in LDS (32KB).
// MFMAs are INLINE ASM with "a" A-operand -> no accvgpr_read copies, no W LDS
// reads for 60/64 fragments. Hazard handling (R4 NaN root cause): s_nop 3 inside
// the FIRST asm block (VALU zero-init -> MFMA srcC read), s_nop 7 x2 inside the
// LAST (MFMA D -> ds_write read). Dependent same-acc MFMAs are 4 apart (c0..c3
// interleave) = safe. ds_read results feed asm as "v" inputs -> compiler inserts
// lgkmcnt waits. Two lgkm-only barriers per step; global traffic lane-private.

#define REP16(M) M(0) M(1) M(2) M(3) M(4) M(5) M(6) M(7) \
                 M(8) M(9) M(10) M(11) M(12) M(13) M(14) M(15)
#define REP12(M) M(0) M(1) M(2) M(3) M(4) M(5) M(6) M(7) \
                 M(8) M(9) M(10) M(11)

#define LDW(jt, kt) (*reinterpret_cast<const bf16x8*>( \
    whhb + (size_t)(w * 64 + (jt) * 16 + r16) * H_SZ + (kt) * 32 + q * 8))

#define DECL3(k) bf16x8 rA##k, rB##k, rC##k;
#define DECLD(k) bf16x8 rD##k;
#define LOAD3(k) { \
    bf16x8 t0 = LDW(0, k), t1 = LDW(1, k), t2 = LDW(2, k); \
    asm("" : "=a"(rA##k) : "0"(t0)); \
    asm("" : "=a"(rB##k) : "0"(t1)); \
    asm("" : "=a"(rC##k) : "0"(t2)); }
#define LOADD(k) { \
    bf16x8 t3 = LDW(3, k); \
    asm("" : "=a"(rD##k) : "0"(t3)); }

#define BF(k) (*reinterpret_cast<const bf16x8*>(hb + (k) * 32 + q * 8))
#define AL(k) (*reinterpret_cast<const bf16x8*>(&WD[(w * 4 + (k) - 12) * 512 + lane * 8]))

#define MFMA4 \
    "v_mfma_f32_16x16x32_bf16 %0, %4, %8, %0\n\t" \
    "v_mfma_f32_16x16x32_bf16 %1, %5, %8, %1\n\t" \
    "v_mfma_f32_16x16x32_bf16 %2, %6, %8, %2\n\t" \
    "v_mfma_f32_16x16x32_bf16 %3, %7, %8, %3"

// kt = 0: leading s_nop covers VALU-zero-init -> MFMA srcC hazard
#define K_FIRST(k) { bf16x8 bf = BF(k); \
    asm("s_nop 3\n\t" MFMA4 \
        : "+v"(c0), "+v"(c1), "+v"(c2), "+v"(c3) \
        : "a"(rA##k), "a"(rB##k), "a"(rC##k), "a"(rD##k), "v"(bf)); }
// kt = 1..11: all-AGPR A operands
#define K_AGPR(k) { bf16x8 bf = BF(k); \
    asm(MFMA4 \
        : "+v"(c0), "+v"(c1), "+v"(c2), "+v"(c3) \
        : "a"(rA##k), "a"(rB##k), "a"(rC##k), "a"(rD##k), "v"(bf)); }
// kt = 12..14: subtile D from LDS
#define K_LDS(k) { bf16x8 bf = BF(k); bf16x8 al = AL(k); \
    asm(MFMA4 \
        : "+v"(c0), "+v"(c1), "+v"(c2), "+v"(c3) \
        : "a"(rA##k), "a"(rB##k), "a"(rC##k), "v"(al), "v"(bf)); }
// kt = 15: trailing s_nops cover MFMA D -> ds_write/VALU read hazard
#define K_LAST(k) { bf16x8 bf = BF(k); bf16x8 al = AL(k); \
    asm(MFMA4 "\n\ts_nop 7\n\ts_nop 7" \
        : "+v"(c0), "+v"(c1), "+v"(c2), "+v"(c3) \
        : "a"(rA##k), "a"(rB##k), "a"(rC##k), "v"(al), "v"(bf)); }

#define STEP(P, XP, sidx, CHKLAST)                                                          \
  {                                                                                          \
    const uint16_t* hb = &hsm[P][0];                                                         \
    f32x4 c0{0.f,0.f,0.f,0.f}, c1{0.f,0.f,0.f,0.f}, c2{0.f,0.f,0.f,0.f}, c3{0.f,0.f,0.f,0.f};\
    K_FIRST(0)                                                                               \
    K_AGPR(1) K_AGPR(2) K_AGPR(3) K_AGPR(4)  K_AGPR(5)  K_AGPR(6)                            \
    K_AGPR(7) K_AGPR(8) K_AGPR(9) K_AGPR(10) K_AGPR(11)                                      \
    K_LDS(12) K_LDS(13) K_LDS(14)                                                            \
    K_LAST(15)                                                                               \
    if (r16 == 0) {                                                                          \
      *reinterpret_cast<f32x4*>(&ysm[w * 64 +  0 + q * 4]) = c0;                             \
      *reinterpret_cast<f32x4*>(&ysm[w * 64 + 16 + q * 4]) = c1;                             \
      *reinterpret_cast<f32x4*>(&ysm[w * 64 + 32 + q * 4]) = c2;                             \
      *reinterpret_cast<f32x4*>(&ysm[w * 64 + 48 + q * 4]) = c3;                             \
    }                                                                                        \
    asm volatile("s_waitcnt lgkmcnt(0)" ::: "memory");                                       \
    __builtin_amdgcn_s_barrier();                                                            \
    float th = tfun(ysm[tid] + XP);                                                          \
    out[((size_t)(sidx) * B_SZ + b) * H_SZ + tid] = th;                                      \
    hsm[(P) ^ 1][tid] = f2b(th);                                                             \
    if (CHKLAST && (sidx) == S_LEN - 1)                                                      \
      out[(size_t)S_LEN * B_SZ * H_SZ + (size_t)b * H_SZ + tid] = th;                        \
    { int prow = ((sidx) + 2 < S_LEN) ? ((sidx) + 2) : 0;                                    \
      XP = out[((size_t)prow * B_SZ + b) * H_SZ + tid]; }                                    \
    asm volatile("s_waitcnt lgkmcnt(0)" ::: "memory");                                       \
    __builtin_amdgcn_s_barrier();                                                            \
  }

__global__ __launch_bounds__(512)
__attribute__((amdgpu_waves_per_eu(2, 2)))
void rnn_rec_kernel(const uint16_t* __restrict__ whhb,  // [H, H] bf16
                    const float* __restrict__ hx,       // [B, H] f32
                    float* __restrict__ out)            // [S*B*H | B*H] f32
{
    __shared__ __align__(16) uint16_t WD[8 * 4 * 512];   // 32 KB: per-wave subtile D kt12..15
    __shared__ __align__(16) uint16_t hsm[2][512];       // h in bf16, double-buffered
    __shared__ __align__(16) float    ysm[512];          // y = Whh @ h

    const int tid  = threadIdx.x;   // 0..511
    const int lane = tid & 63;
    const int w    = tid >> 6;      // wave 0..7 -> rows [w*64, w*64+64)
    const int b    = blockIdx.x;    // batch
    const int r16  = lane & 15;
    const int q    = lane >> 4;     // 0..3

    // W fragments: rows j = w*64 + jt*16 + r16, k = kt*32 + q*8 + e
    REP16(DECL3)
    REP12(DECLD)
    REP16(LOAD3)
    REP12(LOADD)

    // subtile D, kt = 12..15 -> LDS
#pragma unroll
    for (int kt = 12; kt < 16; ++kt)
        *reinterpret_cast<bf16x8*>(&WD[(w * 4 + kt - 12) * 512 + lane * 8]) = LDW(3, kt);

    hsm[0][tid] = f2b(hx[(size_t)b * H_SZ + tid]);

    float xpA = out[((size_t)0 * B_SZ + b) * H_SZ + tid];
    float xpB = out[((size_t)1 * B_SZ + b) * H_SZ + tid];
    __syncthreads();

    for (int s = 0; s < S_LEN; s += 2) {
        STEP(0, xpA, s, 0)
        STEP(1, xpB, s + 1, 1)
    }
}

// ---------------- launcher ----------------
extern "C" void kernel_launch(void* const* d_in, const int* in_sizes, int n_in,
                              void* d_out, int out_size, void* d_ws, size_t ws_size,
                              hipStream_t stream) {
    const float* inp = (const float*)d_in[0];
    const float* hx  = (const float*)d_in[1];
    const float* wih = (const float*)d_in[2];
    const float* whh = (const float*)d_in[3];
    const float* bih = (const float*)d_in[4];
    const float* bhh = (const float*)d_in[5];
    float* out = (float*)d_out;

    uint16_t* wihb = (uint16_t*)d_ws;
    uint16_t* whhb = wihb + (size_t)H_SZ * I_SZ;

    cvt_weights_kernel<<<256, 256, 0, stream>>>(wih, whh, wihb, whhb);

    const int grid_gemm = (S_LEN * B_SZ / BM) * (H_SZ / BN);  // 4096
    xproj_gemm_kernel<<<grid_gemm, 256, 0, stream>>>(inp, wihb, bih, bhh, out);

    rnn_rec_kernel<<<B_SZ, 512, 0, stream>>>(whhb, hx, out);
}

// Round 7
// 4664.166 us; speedup vs baseline: 1.6026x; 1.6026x over previous
//
#include <hip/hip_runtime.h>
#include <stdint.h>

#define S_LEN 2048
#define B_SZ  64
#define I_SZ  512
#define H_SZ  512

typedef __attribute__((ext_vector_type(8))) short bf16x8;
typedef __attribute__((ext_vector_type(4))) float f32x4;

__device__ __forceinline__ uint16_t f2b(float x) {
    uint32_t u = __float_as_uint(x);
    uint32_t r = (u + 0x7fffu + ((u >> 16) & 1u)) >> 16;
    return (uint16_t)r;
}

__device__ __forceinline__ float tfun(float v) {
    float e = __expf(2.f * v);
    return 1.f - 2.f / (e + 1.f);
}

// ---------------- kernel 1: convert W_hh to bf16 in ws ----------------
__global__ void cvt_weights_kernel(const float* __restrict__ whh,
                                   uint16_t* __restrict__ whhb) {
    int i = (blockIdx.x * blockDim.x + threadIdx.x) * 4;   // 256*256*4 = 262144
    float4 b = *reinterpret_cast<const float4*>(whh + i);
    union { uint16_t u[4]; uint2 v; } pb;
    pb.u[0] = f2b(b.x); pb.u[1] = f2b(b.y); pb.u[2] = f2b(b.z); pb.u[3] = f2b(b.w);
    *reinterpret_cast<uint2*>(whhb + i) = pb.v;
}

// ---------------- kernel 2: x_proj GEMM (B converted from f32 on the fly) ----
#define BM 128
#define BN 128
#define BK 32

__launch_bounds__(256)
__global__ void xproj_gemm_kernel(const float* __restrict__ inp,      // [SB, I] f32
                                  const float* __restrict__ wih,      // [H, I] f32
                                  const float* __restrict__ bih,
                                  const float* __restrict__ bhh,
                                  float* __restrict__ xp)             // [SB, H] f32 (= d_out)
{
    __shared__ __align__(16) uint16_t Asm[2][BM * BK];
    __shared__ __align__(16) uint16_t Bsm[2][BN * BK];

    const int tid  = threadIdx.x;
    const int lane = tid & 63;
    const int w    = tid >> 6;
    const int wm   = (w >> 1) * 64;
    const int wn   = (w & 1) * 64;
    const int bid  = blockIdx.x;
    const int m0   = (bid >> 2) * BM;
    const int n0   = (bid & 3) * BN;

    const int srow  = tid >> 1;
    const int shalf = (tid & 1) * 16;

    float bsum[4];
#pragma unroll
    for (int nn = 0; nn < 4; ++nn) {
        int col = n0 + wn + nn * 16 + (lane & 15);
        bsum[nn] = bih[col] + bhh[col];
    }

    f32x4 acc[4][4];
#pragma unroll
    for (int mm = 0; mm < 4; ++mm)
#pragma unroll
        for (int nn = 0; nn < 4; ++nn)
            acc[mm][nn] = f32x4{0.f, 0.f, 0.f, 0.f};

    float4 ar[4], br[4];

    auto loadA = [&](int kt) {
        const float* g = inp + (size_t)(m0 + srow) * I_SZ + kt * BK + shalf;
#pragma unroll
        for (int q = 0; q < 4; ++q) ar[q] = *reinterpret_cast<const float4*>(g + q * 4);
    };
    auto loadB = [&](int kt) {
        const float* g = wih + (size_t)(n0 + srow) * I_SZ + kt * BK + shalf;
#pragma unroll
        for (int q = 0; q < 4; ++q) br[q] = *reinterpret_cast<const float4*>(g + q * 4);
    };
    auto cvt16 = [&](float4* src, uint16_t* dst) {
        alignas(16) uint16_t tmp[16];
#pragma unroll
        for (int q = 0; q < 4; ++q) {
            tmp[q * 4 + 0] = f2b(src[q].x); tmp[q * 4 + 1] = f2b(src[q].y);
            tmp[q * 4 + 2] = f2b(src[q].z); tmp[q * 4 + 3] = f2b(src[q].w);
        }
        *reinterpret_cast<bf16x8*>(dst)     = *reinterpret_cast<bf16x8*>(tmp);
        *reinterpret_cast<bf16x8*>(dst + 8) = *reinterpret_cast<bf16x8*>(tmp + 8);
    };
    auto writeA = [&](int buf) { cvt16(ar, &Asm[buf][srow * BK + shalf]); };
    auto writeB = [&](int buf) { cvt16(br, &Bsm[buf][srow * BK + shalf]); };

    loadA(0); loadB(0); writeA(0); writeB(0);
    __syncthreads();

    for (int kt = 0; kt < I_SZ / BK; ++kt) {
        const int cur = kt & 1;
        const bool more = (kt + 1) < I_SZ / BK;
        if (more) { loadA(kt + 1); loadB(kt + 1); }

        bf16x8 afrag[4], bfrag[4];
#pragma unroll
        for (int mm = 0; mm < 4; ++mm)
            afrag[mm] = *reinterpret_cast<const bf16x8*>(
                &Asm[cur][(wm + mm * 16 + (lane & 15)) * BK + (lane >> 4) * 8]);
#pragma unroll
        for (int nn = 0; nn < 4; ++nn)
            bfrag[nn] = *reinterpret_cast<const bf16x8*>(
                &Bsm[cur][(wn + nn * 16 + (lane & 15)) * BK + (lane >> 4) * 8]);
#pragma unroll
        for (int mm = 0; mm < 4; ++mm)
#pragma unroll
            for (int nn = 0; nn < 4; ++nn)
                acc[mm][nn] = __builtin_amdgcn_mfma_f32_16x16x32_bf16(
                    afrag[mm], bfrag[nn], acc[mm][nn], 0, 0, 0);

        if (more) { writeA(cur ^ 1); writeB(cur ^ 1); }
        __syncthreads();
    }

#pragma unroll
    for (int mm = 0; mm < 4; ++mm) {
        const int rbase = m0 + wm + mm * 16 + (lane >> 4) * 4;
#pragma unroll
        for (int nn = 0; nn < 4; ++nn) {
            const int col = n0 + wn + nn * 16 + (lane & 15);
#pragma unroll
            for (int r = 0; r < 4; ++r)
                xp[(size_t)(rbase + r) * H_SZ + col] = acc[mm][nn][r] + bsum[nn];
        }
    }
}

// ---------------- kernel 3: recurrence ----------------
// LDS-pipe-minimal design. Per CU per step:
//   - W subtiles A,B,C (rows jt=0..2): 192 AGPRs, zero pipe cost (asm MFMA "a" src)
//   - W subtile D (rows 48..63): LDS, 16 ds_read_b128/wave  (the only LDS traffic)
//   - h: bf16 ring in ws (global), 16 global_load_dwordx4/wave on the VMEM pipe
//   - epilogue distributed over lanes r16<4 (each owns one c-frag: all MFMA
//     columns are identical broadcast copies); tanh + float4 out-store + bf16
//     ring-store; xp prefetched 2 steps ahead
//   - one vmcnt(0)+s_barrier per step (ring visibility); no LDS barriers
// Budget: 192 AGPR + ~56 arch VGPR < 256 at waves_per_eu(2,2).

#define REP16(M) M(0) M(1) M(2) M(3) M(4) M(5) M(6) M(7) \
                 M(8) M(9) M(10) M(11) M(12) M(13) M(14) M(15)

#define LDW(jt, kt) (*reinterpret_cast<const bf16x8*>( \
    whhb + (size_t)(w * 64 + (jt) * 16 + r16) * H_SZ + (kt) * 32 + q * 8))

#define DECL3(k) bf16x8 rA##k, rB##k, rC##k;
#define LOAD3(k) { \
    bf16x8 t0 = LDW(0, k), t1 = LDW(1, k), t2 = LDW(2, k); \
    asm("" : "=a"(rA##k) : "0"(t0)); \
    asm("" : "=a"(rB##k) : "0"(t1)); \
    asm("" : "=a"(rC##k) : "0"(t2)); }

#define BF(P, k) (*reinterpret_cast<const bf16x8*>(rbase + (P) * 512 + (k) * 32))
#define AL(k)    (*reinterpret_cast<const bf16x8*>(&WD[(w * 16 + (k)) * 512 + lane * 8]))

#define MFMA4 \
    "v_mfma_f32_16x16x32_bf16 %0, %4, %8, %0\n\t" \
    "v_mfma_f32_16x16x32_bf16 %1, %5, %8, %1\n\t" \
    "v_mfma_f32_16x16x32_bf16 %2, %6, %8, %2\n\t" \
    "v_mfma_f32_16x16x32_bf16 %3, %7, %8, %3"

// first kt: s_nop covers VALU zero-init -> MFMA srcC hazard (R4 NaN root cause)
#define K_FIRST(P, k) { bf16x8 bf = BF(P, k); bf16x8 al = AL(k); \
    asm("s_nop 3\n\t" MFMA4 \
        : "+v"(c0), "+v"(c1), "+v"(c2), "+v"(c3) \
        : "a"(rA##k), "a"(rB##k), "a"(rC##k), "v"(al), "v"(bf)); }
#define K_MID(P, k) { bf16x8 bf = BF(P, k); bf16x8 al = AL(k); \
    asm(MFMA4 \
        : "+v"(c0), "+v"(c1), "+v"(c2), "+v"(c3) \
        : "a"(rA##k), "a"(rB##k), "a"(rC##k), "v"(al), "v"(bf)); }
// last kt: trailing nops cover MFMA -> VALU read of c0..c3
#define K_LAST(P, k) { bf16x8 bf = BF(P, k); bf16x8 al = AL(k); \
    asm(MFMA4 "\n\ts_nop 7\n\ts_nop 7" \
        : "+v"(c0), "+v"(c1), "+v"(c2), "+v"(c3) \
        : "a"(rA##k), "a"(rB##k), "a"(rC##k), "v"(al), "v"(bf)); }

#define STEP(P, XP, sidx, CHKLAST)                                                          \
  {                                                                                          \
    f32x4 c0{0.f,0.f,0.f,0.f}, c1{0.f,0.f,0.f,0.f}, c2{0.f,0.f,0.f,0.f}, c3{0.f,0.f,0.f,0.f};\
    K_FIRST(P, 0)                                                                            \
    K_MID(P, 1)  K_MID(P, 2)  K_MID(P, 3)  K_MID(P, 4)                                       \
    K_MID(P, 5)  K_MID(P, 6)  K_MID(P, 7)  K_MID(P, 8)                                       \
    K_MID(P, 9)  K_MID(P, 10) K_MID(P, 11) K_MID(P, 12)                                      \
    K_MID(P, 13) K_MID(P, 14)                                                                \
    K_LAST(P, 15)                                                                            \
    if (act) {                                                                               \
      f32x4 my = (r16 == 0) ? c0 : (r16 == 1) ? c1 : (r16 == 2) ? c2 : c3;                   \
      float t0 = tfun(my[0] + XP.x), t1 = tfun(my[1] + XP.y);                                \
      float t2 = tfun(my[2] + XP.z), t3 = tfun(my[3] + XP.w);                                \
      *reinterpret_cast<float4*>(out + ((size_t)(sidx) * B_SZ + b) * H_SZ + j0) =            \
          make_float4(t0, t1, t2, t3);                                                       \
      uint2 hp;                                                                              \
      hp.x = (uint32_t)f2b(t0) | ((uint32_t)f2b(t1) << 16);                                  \
      hp.y = (uint32_t)f2b(t2) | ((uint32_t)f2b(t3) << 16);                                  \
      *reinterpret_cast<uint2*>(rwbase + ((P) ^ 1) * 512 + j0) = hp;                         \
      if (CHKLAST && (sidx) == S_LEN - 1)                                                    \
        *reinterpret_cast<float4*>(out + (size_t)S_LEN * B_SZ * H_SZ +                       \
                                   (size_t)b * H_SZ + j0) = make_float4(t0, t1, t2, t3);     \
      int prow = ((sidx) + 2 < S_LEN) ? ((sidx) + 2) : 0;                                    \
      XP = *reinterpret_cast<const float4*>(out + ((size_t)prow * B_SZ + b) * H_SZ + j0);    \
    }                                                                                        \
    asm volatile("s_waitcnt vmcnt(0)" ::: "memory");                                         \
    __builtin_amdgcn_s_barrier();                                                            \
  }

__global__ __launch_bounds__(512)
__attribute__((amdgpu_waves_per_eu(2, 2)))
void rnn_rec_kernel(const uint16_t* __restrict__ whhb,  // [H, H] bf16
                    uint16_t* __restrict__ hring,       // [B][2][H] bf16 ring
                    const float* __restrict__ hx,       // [B, H] f32
                    float* __restrict__ out)            // [S*B*H | B*H] f32
{
    __shared__ __align__(16) uint16_t WD[8 * 16 * 512];  // 128 KB: per-wave subtile D

    const int tid  = threadIdx.x;   // 0..511
    const int lane = tid & 63;
    const int w    = tid >> 6;      // wave 0..7 -> rows [w*64, w*64+64)
    const int b    = blockIdx.x;    // batch
    const int r16  = lane & 15;
    const int q    = lane >> 4;     // 0..3

    // W fragments A,B,C pinned in AGPRs: rows j = w*64 + jt*16 + r16
    REP16(DECL3)
    REP16(LOAD3)

    // subtile D (rows w*64+48..63) -> LDS
#pragma unroll
    for (int kt = 0; kt < 16; ++kt)
        *reinterpret_cast<bf16x8*>(&WD[(w * 16 + kt) * 512 + lane * 8]) = LDW(3, kt);

    // seed ring slot 0 with h(-1) = hx (bf16); every thread writes one element
    uint16_t* rwbase = hring + (size_t)b * 1024;        // ring[b][0]
    rwbase[tid < 512 ? tid : 0] = f2b(hx[(size_t)b * H_SZ + tid]);
    // NOTE: write via slot-0 base then flip parity inside STEP via ^1 on writes
    const uint16_t* rbase = hring + (size_t)b * 1024 + q * 8;   // + kt*32 per frag

    // epilogue ownership: lane (q, r16=f) owns c-frag f -> rows j0..j0+3
    const bool act = (r16 < 4);
    const int  j0  = w * 64 + r16 * 16 + q * 4;

    float4 xpA = make_float4(0.f, 0.f, 0.f, 0.f);
    float4 xpB = make_float4(0.f, 0.f, 0.f, 0.f);
    if (act) {
        xpA = *reinterpret_cast<const float4*>(out + ((size_t)0 * B_SZ + b) * H_SZ + j0);
        xpB = *reinterpret_cast<const float4*>(out + ((size_t)1 * B_SZ + b) * H_SZ + j0);
    }
    asm volatile("s_waitcnt vmcnt(0) lgkmcnt(0)" ::: "memory");
    __builtin_amdgcn_s_barrier();

    // step s: reads ring[s&1], writes ring[(s&1)^1]
    for (int s = 0; s < S_LEN; s += 2) {
        STEP(0, xpA, s, 0)
        STEP(1, xpB, s + 1, 1)
    }
}

// ---------------- launcher ----------------
extern "C" void kernel_launch(void* const* d_in, const int* in_sizes, int n_in,
                              void* d_out, int out_size, void* d_ws, size_t ws_size,
                              hipStream_t stream) {
    const float* inp = (const float*)d_in[0];
    const float* hx  = (const float*)d_in[1];
    const float* wih = (const float*)d_in[2];
    const float* whh = (const float*)d_in[3];
    const float* bih = (const float*)d_in[4];
    const float* bhh = (const float*)d_in[5];
    float* out = (float*)d_out;

    uint16_t* whhb  = (uint16_t*)d_ws;                       // 512 KB
    uint16_t* hring = whhb + (size_t)H_SZ * H_SZ;            // +128 KB (64 x 2 x 512)

    cvt_weights_kernel<<<256, 256, 0, stream>>>(whh, whhb);

    const int grid_gemm = (S_LEN * B_SZ / BM) * (H_SZ / BN);  // 4096
    xproj_gemm_kernel<<<grid_gemm, 256, 0, stream>>>(inp, wih, bih, bhh, out);

    rnn_rec_kernel<<<B_SZ, 512, 0, stream>>>(whhb, hring, hx, out);
}

// Round 9
// 4642.342 us; speedup vs baseline: 1.6101x; 1.0047x over previous
//
#include <hip/hip_runtime.h>
#include <stdint.h>

#define S_LEN 2048
#define B_SZ  64
#define I_SZ  512
#define H_SZ  512

typedef __attribute__((ext_vector_type(8))) short bf16x8;
typedef __attribute__((ext_vector_type(4))) float f32x4;
typedef __attribute__((ext_vector_type(2))) unsigned int u32x2;

__device__ __forceinline__ uint16_t f2b(float x) {
    uint32_t u = __float_as_uint(x);
    uint32_t r = (u + 0x7fffu + ((u >> 16) & 1u)) >> 16;
    return (uint16_t)r;
}

__device__ __forceinline__ float tfun(float v) {
    float e = __expf(2.f * v);
    return 1.f - 2.f / (e + 1.f);
}

// ---------------- kernel 1: convert W_hh to bf16 in ws ----------------
__global__ void cvt_weights_kernel(const float* __restrict__ whh,
                                   uint16_t* __restrict__ whhb) {
    int i = (blockIdx.x * blockDim.x + threadIdx.x) * 4;
    float4 b = *reinterpret_cast<const float4*>(whh + i);
    union { uint16_t u[4]; uint2 v; } pb;
    pb.u[0] = f2b(b.x); pb.u[1] = f2b(b.y); pb.u[2] = f2b(b.z); pb.u[3] = f2b(b.w);
    *reinterpret_cast<uint2*>(whhb + i) = pb.v;
}

// ---------------- kernel 2: x_proj GEMM (f32 in, cvt on the fly) ----
#define BM 128
#define BN 128
#define BK 32

__launch_bounds__(256)
__global__ void xproj_gemm_kernel(const float* __restrict__ inp,      // [SB, I] f32
                                  const float* __restrict__ wih,      // [H, I] f32
                                  const float* __restrict__ bih,
                                  const float* __restrict__ bhh,
                                  float* __restrict__ xp)             // [SB, H] f32 (= d_out)
{
    __shared__ __align__(16) uint16_t Asm[2][BM * BK];
    __shared__ __align__(16) uint16_t Bsm[2][BN * BK];

    const int tid  = threadIdx.x;
    const int lane = tid & 63;
    const int w    = tid >> 6;
    const int wm   = (w >> 1) * 64;
    const int wn   = (w & 1) * 64;
    const int bid  = blockIdx.x;
    const int m0   = (bid >> 2) * BM;
    const int n0   = (bid & 3) * BN;

    const int srow  = tid >> 1;
    const int shalf = (tid & 1) * 16;

    float bsum[4];
#pragma unroll
    for (int nn = 0; nn < 4; ++nn) {
        int col = n0 + wn + nn * 16 + (lane & 15);
        bsum[nn] = bih[col] + bhh[col];
    }

    f32x4 acc[4][4];
#pragma unroll
    for (int mm = 0; mm < 4; ++mm)
#pragma unroll
        for (int nn = 0; nn < 4; ++nn)
            acc[mm][nn] = f32x4{0.f, 0.f, 0.f, 0.f};

    float4 ar[4], br[4];

    auto loadA = [&](int kt) {
        const float* g = inp + (size_t)(m0 + srow) * I_SZ + kt * BK + shalf;
#pragma unroll
        for (int q = 0; q < 4; ++q) ar[q] = *reinterpret_cast<const float4*>(g + q * 4);
    };
    auto loadB = [&](int kt) {
        const float* g = wih + (size_t)(n0 + srow) * I_SZ + kt * BK + shalf;
#pragma unroll
        for (int q = 0; q < 4; ++q) br[q] = *reinterpret_cast<const float4*>(g + q * 4);
    };
    auto cvt16 = [&](float4* src, uint16_t* dst) {
        alignas(16) uint16_t tmp[16];
#pragma unroll
        for (int q = 0; q < 4; ++q) {
            tmp[q * 4 + 0] = f2b(src[q].x); tmp[q * 4 + 1] = f2b(src[q].y);
            tmp[q * 4 + 2] = f2b(src[q].z); tmp[q * 4 + 3] = f2b(src[q].w);
        }
        *reinterpret_cast<bf16x8*>(dst)     = *reinterpret_cast<bf16x8*>(tmp);
        *reinterpret_cast<bf16x8*>(dst + 8) = *reinterpret_cast<bf16x8*>(tmp + 8);
    };
    auto writeA = [&](int buf) { cvt16(ar, &Asm[buf][srow * BK + shalf]); };
    auto writeB = [&](int buf) { cvt16(br, &Bsm[buf][srow * BK + shalf]); };

    loadA(0); loadB(0); writeA(0); writeB(0);
    __syncthreads();

    for (int kt = 0; kt < I_SZ / BK; ++kt) {
        const int cur = kt & 1;
        const bool more = (kt + 1) < I_SZ / BK;
        if (more) { loadA(kt + 1); loadB(kt + 1); }

        bf16x8 afrag[4], bfrag[4];
#pragma unroll
        for (int mm = 0; mm < 4; ++mm)
            afrag[mm] = *reinterpret_cast<const bf16x8*>(
                &Asm[cur][(wm + mm * 16 + (lane & 15)) * BK + (lane >> 4) * 8]);
#pragma unroll
        for (int nn = 0; nn < 4; ++nn)
            bfrag[nn] = *reinterpret_cast<const bf16x8*>(
                &Bsm[cur][(wn + nn * 16 + (lane & 15)) * BK + (lane >> 4) * 8]);
#pragma unroll
        for (int mm = 0; mm < 4; ++mm)
#pragma unroll
            for (int nn = 0; nn < 4; ++nn)
                acc[mm][nn] = __builtin_amdgcn_mfma_f32_16x16x32_bf16(
                    afrag[mm], bfrag[nn], acc[mm][nn], 0, 0, 0);

        if (more) { writeA(cur ^ 1); writeB(cur ^ 1); }
        __syncthreads();
    }

#pragma unroll
    for (int mm = 0; mm < 4; ++mm) {
        const int rbase = m0 + wm + mm * 16 + (lane >> 4) * 4;
#pragma unroll
        for (int nn = 0; nn < 4; ++nn) {
            const int col = n0 + wn + nn * 16 + (lane & 15);
#pragma unroll
            for (int r = 0; r < 4; ++r)
                xp[(size_t)(rbase + r) * H_SZ + col] = acc[mm][nn][r] + bsum[nn];
        }
    }
}

// ---------------- kernel 3: recurrence ----------------
// Pipe-balanced design (model: step time ~= #ds_read_b128 per CU x 12cyc):
//   - W jt0..2 (48 frags): 192 AGPRs via empty-asm pin + asm MFMA "a" src (R7-proven)
//   - W jt3 (16 frags): LDS, 16 ds_read_b128/lane -> the ONLY LDS traffic
//   - h: bf16 ring in ws (2 slots x 512, L1/L2-hot), 16 VMEM b128 loads/lane,
//     4-deep register ping-pong -> VMEM pipe overlaps the LDS stream
//   - epilogue: act lanes (r16<4) own one c-frag (MFMA columns are broadcast
//     copies); tanh; asm-ordered [ring-store(8B), out-store(16B), xp-load(16B)]
//     then counted s_waitcnt vmcnt(2): ring-store retired, HBM out-store floats
//   - ONE barrier per step. All asm operands are ext_vector types (R8 compile
//     fix: HIP float4/uint2 classes are passed indirectly -> illegal for "v").

#define REP16(M) M(0) M(1) M(2) M(3) M(4) M(5) M(6) M(7) \
                 M(8) M(9) M(10) M(11) M(12) M(13) M(14) M(15)

#define LDW(jt, kt) (*reinterpret_cast<const bf16x8*>( \
    whhb + (size_t)(w * 64 + (jt) * 16 + r16) * H_SZ + (kt) * 32 + q * 8))

#define DECL3(k) bf16x8 rA##k, rB##k, rC##k;
#define LOAD3(k) { \
    bf16x8 t0 = LDW(0, k), t1 = LDW(1, k), t2 = LDW(2, k); \
    asm("" : "=a"(rA##k) : "0"(t0)); \
    asm("" : "=a"(rB##k) : "0"(t1)); \
    asm("" : "=a"(rC##k) : "0"(t2)); }

#define HRD(P, k) (*reinterpret_cast<const bf16x8*>(ringrd + (P) * 512 + (k) * 32))
#define AL(k)     (*reinterpret_cast<const bf16x8*>(&WD[(w * 16 + (k)) * 512 + lane * 8]))

#define MFMA4 \
    "v_mfma_f32_16x16x32_bf16 %0, %4, %8, %0\n\t" \
    "v_mfma_f32_16x16x32_bf16 %1, %5, %8, %1\n\t" \
    "v_mfma_f32_16x16x32_bf16 %2, %6, %8, %2\n\t" \
    "v_mfma_f32_16x16x32_bf16 %3, %7, %8, %3"

// leading s_nop covers VALU zero-init -> MFMA srcC hazard (R4 lesson, R7-proven)
#define KF(k, H) { bf16x8 al = AL(k); \
    asm("s_nop 3\n\t" MFMA4 \
        : "+v"(c0), "+v"(c1), "+v"(c2), "+v"(c3) \
        : "a"(rA##k), "a"(rB##k), "a"(rC##k), "v"(al), "v"(H)); }
#define KM(k, H) { bf16x8 al = AL(k); \
    asm(MFMA4 \
        : "+v"(c0), "+v"(c1), "+v"(c2), "+v"(c3) \
        : "a"(rA##k), "a"(rB##k), "a"(rC##k), "v"(al), "v"(H)); }
// trailing s_nops cover MFMA D -> VALU read hazard (R7-proven)
#define KL(k, H) { bf16x8 al = AL(k); \
    asm(MFMA4 "\n\ts_nop 7\n\ts_nop 7" \
        : "+v"(c0), "+v"(c1), "+v"(c2), "+v"(c3) \
        : "a"(rA##k), "a"(rB##k), "a"(rC##k), "v"(al), "v"(H)); }

// OP: out row sidx (store). XPP: out row sidx+1 (xp prefetch; at the final
// step XPP = row 2048 = the h_last tail region).
#define STEP(P, OFFSTR, OP, XPP, sidx, CHKLAST)                                              \
  {                                                                                          \
    bf16x8 h0 = HRD(P, 0), h1 = HRD(P, 1), h2 = HRD(P, 2), h3 = HRD(P, 3);                   \
    f32x4 c0{0.f,0.f,0.f,0.f}, c1{0.f,0.f,0.f,0.f}, c2{0.f,0.f,0.f,0.f}, c3{0.f,0.f,0.f,0.f};\
    KF(0, h0)  h0 = HRD(P, 4);                                                               \
    KM(1, h1)  h1 = HRD(P, 5);                                                               \
    KM(2, h2)  h2 = HRD(P, 6);                                                               \
    KM(3, h3)  h3 = HRD(P, 7);                                                               \
    KM(4, h0)  h0 = HRD(P, 8);                                                               \
    KM(5, h1)  h1 = HRD(P, 9);                                                               \
    KM(6, h2)  h2 = HRD(P, 10);                                                              \
    KM(7, h3)  h3 = HRD(P, 11);                                                              \
    KM(8, h0)  h0 = HRD(P, 12);                                                              \
    KM(9, h1)  h1 = HRD(P, 13);                                                              \
    KM(10, h2) h2 = HRD(P, 14);                                                              \
    KM(11, h3) h3 = HRD(P, 15);                                                              \
    KM(12, h0) KM(13, h1) KM(14, h2) KL(15, h3)                                              \
    if (act) {                                                                               \
      f32x4 my = (r16 == 0) ? c0 : (r16 == 1) ? c1 : (r16 == 2) ? c2 : c3;                   \
      f32x4 o4;                                                                              \
      o4[0] = tfun(my[0] + XP[0]); o4[1] = tfun(my[1] + XP[1]);                              \
      o4[2] = tfun(my[2] + XP[2]); o4[3] = tfun(my[3] + XP[3]);                              \
      u32x2 hp;                                                                              \
      hp[0] = (uint32_t)f2b(o4[0]) | ((uint32_t)f2b(o4[1]) << 16);                           \
      hp[1] = (uint32_t)f2b(o4[2]) | ((uint32_t)f2b(o4[3]) << 16);                           \
      asm volatile("global_store_dwordx2 %0, %1, off " OFFSTR                                \
                   :: "v"(rwp), "v"(hp) : "memory");                                         \
      asm volatile("global_store_dwordx4 %0, %1, off"                                        \
                   :: "v"(OP), "v"(o4) : "memory");                                          \
      asm volatile("global_load_dwordx4 %0, %1, off"                                         \
                   : "=v"(XP) : "v"(XPP) : "memory");                                        \
      if (CHKLAST && (sidx) == S_LEN - 1)                                                    \
        *reinterpret_cast<f32x4*>(XPP) = o4;                                                 \
    }                                                                                        \
    asm volatile("s_waitcnt vmcnt(2)" ::: "memory");                                         \
    __builtin_amdgcn_s_barrier();                                                            \
  }

__global__ __launch_bounds__(512)
__attribute__((amdgpu_waves_per_eu(2, 2)))
void rnn_rec_kernel(const uint16_t* __restrict__ whhb,  // [H, H] bf16
                    uint16_t* __restrict__ hring,       // [B][2][512] bf16 ring
                    const float* __restrict__ hx,       // [B, H] f32
                    float* __restrict__ out)            // [S*B*H | B*H] f32
{
    __shared__ __align__(16) uint16_t WD[8 * 16 * 512];  // 128 KB: per-wave W jt3

    const int tid  = threadIdx.x;   // 0..511
    const int lane = tid & 63;
    const int w    = tid >> 6;      // wave 0..7 -> rows [w*64, w*64+64)
    const int b    = blockIdx.x;    // batch
    const int r16  = lane & 15;
    const int q    = lane >> 4;     // 0..3

    // W jt0..2 pinned in AGPRs: rows j = w*64 + jt*16 + r16, k = kt*32 + q*8 + e
    REP16(DECL3)
    REP16(LOAD3)

    // W jt3 (rows w*64+48..63) -> LDS
#pragma unroll
    for (int kt = 0; kt < 16; ++kt)
        *reinterpret_cast<bf16x8*>(&WD[(w * 16 + kt) * 512 + lane * 8]) = LDW(3, kt);

    // h ring: slot0 seeded with hx (bf16)
    uint16_t* ringb = hring + (size_t)b * 1024;
    ringb[tid] = f2b(hx[(size_t)b * H_SZ + tid]);
    const uint16_t* ringrd = ringb + q * 8;               // + P*512 + kt*32 per frag
    uint16_t* rwp = ringb + (w * 64 + r16 * 16 + q * 4);  // element j0; slot via imm

    // epilogue ownership: lanes r16<4 own c-frag r16 -> rows j0..j0+3
    const bool act = (r16 < 4);
    const int  j0  = w * 64 + r16 * 16 + q * 4;

    float* opA = out + (size_t)b * H_SZ + j0;    // row 0 (advances by 2 rows)
    float* opB = opA + (size_t)B_SZ * H_SZ;      // row 1
    f32x4 XP{0.f, 0.f, 0.f, 0.f};
    if (act) XP = *reinterpret_cast<const f32x4*>(opA);   // xp row 0

    asm volatile("s_waitcnt vmcnt(0) lgkmcnt(0)" ::: "memory");
    __builtin_amdgcn_s_barrier();

    for (int s = 0; s < S_LEN; s += 2) {
        STEP(0, "offset:1024", opA, opB, s, 0)        // reads slot0, writes slot1
        opA += 2 * (size_t)B_SZ * H_SZ;               // -> row s+2
        STEP(1, "offset:0",    opB, opA, s + 1, 1)    // reads slot1, writes slot0
        opB += 2 * (size_t)B_SZ * H_SZ;               // -> row s+3
    }
}

// ---------------- launcher ----------------
extern "C" void kernel_launch(void* const* d_in, const int* in_sizes, int n_in,
                              void* d_out, int out_size, void* d_ws, size_t ws_size,
                              hipStream_t stream) {
    const float* inp = (const float*)d_in[0];
    const float* hx  = (const float*)d_in[1];
    const float* wih = (const float*)d_in[2];
    const float* whh = (const float*)d_in[3];
    const float* bih = (const float*)d_in[4];
    const float* bhh = (const float*)d_in[5];
    float* out = (float*)d_out;

    uint16_t* whhb  = (uint16_t*)d_ws;                   // 512 KB
    uint16_t* hring = whhb + (size_t)H_SZ * H_SZ;        // +128 KB

    cvt_weights_kernel<<<256, 256, 0, stream>>>(whh, whhb);

    const int grid_gemm = (S_LEN * B_SZ / BM) * (H_SZ / BN);  // 4096
    xproj_gemm_kernel<<<grid_gemm, 256, 0, stream>>>(inp, wih, bih, bhh, out);

    rnn_rec_kernel<<<B_SZ, 512, 0, stream>>>(whhb, hring, hx, out);
}